// Round 3
// baseline (2138.326 us; speedup 1.0000x reference)
//
#include <hip/hip_runtime.h>

#define Nn 4096
#define Dd 512
#define Ee 65536
#define HOPS 10
#define TPB 512
#define RPT (Nn / TPB)  // 8 rows per thread
#define CT 4            // columns per block
#define TSLOT 20        // ELL cap; rows with deg_in+1 > 20 overflow to sidecar
#define OVPT 5          // overflow edges held per thread
#define OVCAP (OVPT * TPB)  // 2560 (expected ~1700, 8+ sigma margin)
#define AUXCAP 960      // overflow-destination rows (expected ~780, 7 sigma)

// ---------------- sq[i] = sum_d w_d * x[i,d]^2 ----------------
__global__ __launch_bounds__(256) void k_sq(const float* __restrict__ x,
                                            const float* __restrict__ w,
                                            float* __restrict__ sq) {
  int row = blockIdx.x;
  int tid = threadIdx.x;
  const float* xr = x + (size_t)row * Dd;
  float partial = 0.f;
  for (int d = tid; d < Dd; d += 256) {
    float xv = xr[d];
    partial += xv * xv * w[d];
  }
  for (int off = 32; off >= 1; off >>= 1) partial += __shfl_down(partial, off, 64);
  __shared__ float red[4];
  int wv = tid >> 6, ln = tid & 63;
  if (ln == 0) red[wv] = partial;
  __syncthreads();
  if (tid == 0) sq[row] = red[0] + red[1] + red[2] + red[3];
}

// ---------------- K = sq_i + sq_j - 2 * (x*w) @ x^T ; diag -> 1 ----------------
__global__ __launch_bounds__(256) void k_gemm(const float* __restrict__ X,
                                              const float* __restrict__ w,
                                              const float* __restrict__ sq,
                                              float* __restrict__ C) {
  __shared__ float As[8][128];
  __shared__ float Bs[8][128];
  int i0 = blockIdx.y * 128, j0 = blockIdx.x * 128;
  int tid = threadIdx.x;
  int ty = tid >> 4, tx = tid & 15;
  int lr = tid >> 1, lk = (tid & 1) * 4;
  float acc[8][8];
#pragma unroll
  for (int a = 0; a < 8; a++)
#pragma unroll
    for (int b = 0; b < 8; b++) acc[a][b] = 0.f;

  for (int k0 = 0; k0 < Dd; k0 += 8) {
    float4 wv4 = *(const float4*)&w[k0 + lk];
    float4 av4 = *(const float4*)&X[(size_t)(i0 + lr) * Dd + k0 + lk];
    float4 bv4 = *(const float4*)&X[(size_t)(j0 + lr) * Dd + k0 + lk];
    As[lk + 0][lr] = av4.x * wv4.x; As[lk + 1][lr] = av4.y * wv4.y;
    As[lk + 2][lr] = av4.z * wv4.z; As[lk + 3][lr] = av4.w * wv4.w;
    Bs[lk + 0][lr] = bv4.x; Bs[lk + 1][lr] = bv4.y; Bs[lk + 2][lr] = bv4.z; Bs[lk + 3][lr] = bv4.w;
    __syncthreads();
#pragma unroll
    for (int kk = 0; kk < 8; kk++) {
      float av[8], bv[8];
      *(float4*)&av[0] = *(const float4*)&As[kk][ty * 8];
      *(float4*)&av[4] = *(const float4*)&As[kk][ty * 8 + 4];
      *(float4*)&bv[0] = *(const float4*)&Bs[kk][tx * 8];
      *(float4*)&bv[4] = *(const float4*)&Bs[kk][tx * 8 + 4];
#pragma unroll
      for (int a = 0; a < 8; a++)
#pragma unroll
        for (int b = 0; b < 8; b++) acc[a][b] += av[a] * bv[b];
    }
    __syncthreads();
  }
#pragma unroll
  for (int a = 0; a < 8; a++) {
    int gi = i0 + ty * 8 + a;
    float sqi = sq[gi];
    float outv[8];
#pragma unroll
    for (int b = 0; b < 8; b++) {
      int gj = j0 + tx * 8 + b;
      float v = sqi + sq[gj] - 2.f * acc[a][b];
      outv[b] = (gi == gj) ? 1.0f : v;
    }
    float* Cr = &C[(size_t)gi * Nn + j0 + tx * 8];
    *(float4*)&Cr[0] = *(float4*)&outv[0];
    *(float4*)&Cr[4] = *(float4*)&outv[4];
  }
}

// ---------------- degree counting ----------------
__global__ void k_count(const int* __restrict__ src, const int* __restrict__ dst,
                        int* __restrict__ degi, int* __restrict__ degrow) {
  int e = blockIdx.x * blockDim.x + threadIdx.x;
  if (e < Ee) {
    atomicAdd(&degi[dst[e]], 1);
    atomicAdd(&degrow[src[e]], 1);
  }
}

// ---------------- dis = (deg_in+1)^-0.5 ; assign aux slots to overflow rows ----------------
__global__ void k_dis_aux(const int* __restrict__ degi, float* __restrict__ dis,
                          int* __restrict__ auxid, int* __restrict__ auxcnt) {
  int i = blockIdx.x * 256 + threadIdx.x;
  int d = degi[i] + 1;
  dis[i] = rsqrtf((float)d);
  auxid[i] = (d > TSLOT) ? atomicAdd(auxcnt, 1) : -1;
}

// ---------------- ELL fill (slot-major, cap TSLOT) + overflow sidecar list ----------------
// vals pre-scaled by 0.5 (the (1-alpha) factor); dummy slots {0,0} broadcast-free.
__global__ void k_fill_ell(const int* __restrict__ src, const int* __restrict__ dst,
                           const float* __restrict__ dis, const int* __restrict__ auxid,
                           int* __restrict__ slot, int* __restrict__ ovcnt,
                           int2* __restrict__ ell, int2* __restrict__ ov) {
  int i = blockIdx.x * blockDim.x + threadIdx.x;
  int s, d;
  if (i < Ee) { s = src[i]; d = dst[i]; }
  else if (i < Ee + Nn) { s = i - Ee; d = s; }
  else return;
  float val = 0.5f * dis[s] * dis[d];
  int p = atomicAdd(&slot[d], 1);
  if (p < TSLOT) {
    ell[(size_t)p * Nn + d] = make_int2(s, __float_as_int(val));
  } else {
    int q = atomicAdd(ovcnt, 1);
    int a = auxid[d];
    if (q < OVCAP && a >= 0 && a < AUXCAP)
      ov[q] = make_int2(s | (a << 12), __float_as_int(val));
  }
}

// ---------------- fused 10-hop APPNP on a 4-column slab; h resident in LDS ----------------
// Per hop: phase A = capped-ELL register gather (20 slots, 8 independent chains)
//          + overflow edges atomically accumulated into aux (reads h_t, writes aux only);
// barrier; phase B = owners fold aux into acc, store h_{t+1}, clear aux; barrier.
// PASS 1: xsrc=K (symmetric -> column read == row read), writes kgg1 row-major.
// PASS 2: xsrc=dst=kgg1 IN PLACE: block reads rows j0..j0+3 at start, writes them at end.
template <int PASS>
__global__ __launch_bounds__(TPB, 4) void k_appnp(const float* __restrict__ xsrc,
                                                  float* __restrict__ dst,
                                                  const int2* __restrict__ ell,
                                                  const int2* __restrict__ ov,
                                                  const int* __restrict__ ovcnt,
                                                  const int* __restrict__ auxid,
                                                  const int* __restrict__ degrow) {
  extern __shared__ float4 lds[];
  float4* h4 = lds;        // Nn entries, 64 KB
  float4* aux = lds + Nn;  // AUXCAP entries, 15 KB
  int j0 = blockIdx.x * CT;
  int tid = threadIdx.x;
  float4 x0h[RPT];
  int axr[RPT];
#pragma unroll
  for (int rr = 0; rr < RPT; rr++) {
    int r = tid + rr * TPB;
    float4 v;
    v.x = xsrc[(size_t)(j0 + 0) * Nn + r];
    v.y = xsrc[(size_t)(j0 + 1) * Nn + r];
    v.z = xsrc[(size_t)(j0 + 2) * Nn + r];
    v.w = xsrc[(size_t)(j0 + 3) * Nn + r];
    h4[r] = v;
    x0h[rr] = make_float4(0.5f * v.x, 0.5f * v.y, 0.5f * v.z, 0.5f * v.w);
    axr[rr] = auxid[r];
  }
  for (int i = tid; i < AUXCAP; i += TPB) aux[i] = make_float4(0.f, 0.f, 0.f, 0.f);
  int ovn = min(*ovcnt, OVCAP);
  int2 ove[OVPT];
  int nov = 0;
#pragma unroll
  for (int i = 0; i < OVPT; i++) {
    int k = tid + i * TPB;
    if (k < ovn) { ove[i] = ov[k]; nov = i + 1; }
  }
  __syncthreads();

  float4 acc[RPT];
  for (int it = 0; it < HOPS; it++) {
#pragma unroll
    for (int rr = 0; rr < RPT; rr++) acc[rr] = x0h[rr];
    // phase A: main capped-ELL gather (reads h_t)
#pragma unroll 2
    for (int s = 0; s < TSLOT; s++) {
      int2 e[RPT];
#pragma unroll
      for (int rr = 0; rr < RPT; rr++) e[rr] = ell[(size_t)s * Nn + tid + rr * TPB];
#pragma unroll
      for (int rr = 0; rr < RPT; rr++) {
        float vv = __int_as_float(e[rr].y);
        float4 hu = h4[e[rr].x];
        acc[rr].x = fmaf(vv, hu.x, acc[rr].x);
        acc[rr].y = fmaf(vv, hu.y, acc[rr].y);
        acc[rr].z = fmaf(vv, hu.z, acc[rr].z);
        acc[rr].w = fmaf(vv, hu.w, acc[rr].w);
      }
    }
    // phase A cont.: overflow edges -> aux (reads h_t, writes aux)
#pragma unroll
    for (int i = 0; i < OVPT; i++) {
      if (i < nov) {
        int sidx = ove[i].x & 0xFFF;
        int aidx = ove[i].x >> 12;
        float vv = __int_as_float(ove[i].y);
        float4 hu = h4[sidx];
        atomicAdd(&aux[aidx].x, vv * hu.x);
        atomicAdd(&aux[aidx].y, vv * hu.y);
        atomicAdd(&aux[aidx].z, vv * hu.z);
        atomicAdd(&aux[aidx].w, vv * hu.w);
      }
    }
    __syncthreads();
    // phase B: fold aux, store h_{t+1}, clear aux
#pragma unroll
    for (int rr = 0; rr < RPT; rr++) {
      int a = axr[rr];
      if (a >= 0) {
        float4 av = aux[a];
        acc[rr].x += av.x; acc[rr].y += av.y; acc[rr].z += av.z; acc[rr].w += av.w;
        aux[a] = make_float4(0.f, 0.f, 0.f, 0.f);
      }
      h4[tid + rr * TPB] = acc[rr];
    }
    __syncthreads();
  }
  // epilogue: acc holds final h for this thread's rows
  if (PASS == 1) {
#pragma unroll
    for (int rr = 0; rr < RPT; rr++) {
      int r = tid + rr * TPB;
      *(float4*)&dst[(size_t)r * Nn + j0] = acc[rr];
    }
  } else {
#pragma unroll
    for (int rr = 0; rr < RPT; rr++) {
      int r = tid + rr * TPB;
      float vals[4] = {acc[rr].x, acc[rr].y, acc[rr].z, acc[rr].w};
#pragma unroll
      for (int c = 0; c < 4; c++) {
        float v = vals[c];
        if (r == j0 + c) v *= 1.0f / ((float)degrow[r] + 1.0f);
        dst[(size_t)(j0 + c) * Nn + r] = v;
      }
    }
  }
}

extern "C" void kernel_launch(void* const* d_in, const int* in_sizes, int n_in,
                              void* d_out, int out_size, void* d_ws, size_t ws_size,
                              hipStream_t stream) {
  const float* x = (const float*)d_in[0];  // [N,D]
  const float* w = (const float*)d_in[1];  // [D]
  const int* ei = (const int*)d_in[2];     // [2,E]
  const int* src = ei;
  const int* dstv = ei + Ee;
  float* out = (float*)d_out;

  // workspace layout (~66 MB)
  float* W1 = (float*)d_ws;                        // Nn*Nn : K
  float* sq = W1 + (size_t)Nn * Nn;                // Nn
  float* dis = sq + Nn;                            // Nn
  int2* ell = (int2*)(dis + Nn);                   // TSLOT*Nn (640 KB)
  int2* ov = ell + (size_t)TSLOT * Nn;             // OVCAP (20 KB)
  int* auxid = (int*)(ov + OVCAP);                 // Nn
  int* degi = auxid + Nn;                          // Nn
  int* degrow = degi + Nn;                         // Nn
  int* slotcnt = degrow + Nn;                      // Nn
  int* ovcnt = slotcnt + Nn;                       // 1
  int* auxcnt = ovcnt + 1;                         // 1

  hipMemsetAsync(ell, 0, (size_t)TSLOT * Nn * sizeof(int2), stream);
  hipMemsetAsync(degi, 0, sizeof(int) * (3 * Nn + 2), stream);

  k_sq<<<Nn, 256, 0, stream>>>(x, w, sq);
  k_gemm<<<dim3(Nn / 128, Nn / 128), 256, 0, stream>>>(x, w, sq, W1);
  k_count<<<Ee / 256, 256, 0, stream>>>(src, dstv, degi, degrow);
  k_dis_aux<<<Nn / 256, 256, 0, stream>>>(degi, dis, auxid, auxcnt);
  k_fill_ell<<<(Ee + Nn + 255) / 256, 256, 0, stream>>>(src, dstv, dis, auxid,
                                                        slotcnt, ovcnt, ell, ov);

  size_t lds_bytes = (size_t)(Nn + AUXCAP) * sizeof(float4);  // 79 KB -> 2 blocks/CU
  // pass 1: kgg1 = APPNP(K) -> out (row-major)
  k_appnp<1><<<Nn / CT, TPB, lds_bytes, stream>>>(W1, out, ell, ov, ovcnt, auxid, nullptr);
  // pass 2: in-place on out: reads kgg1 rows, writes final (kgg2^T, diag-scaled)
  k_appnp<2><<<Nn / CT, TPB, lds_bytes, stream>>>(out, out, ell, ov, ovcnt, auxid, degrow);
}